// Round 1
// 153.157 us; speedup vs baseline: 1.0660x; 1.0660x over previous
//
#include <hip/hip_runtime.h>
#include <hip/hip_fp16.h>

// SSIM loss, fused, MFMA-blur version. fp32 in [16,3,512,512], fp32 scalar out.
// Round-7 postmortem: VALUBusy 61%, MfmaUtil 0, HBM 16% -> VALU-issue-bound on
// the two separable 11-tap blurs; matrix pipe idle. Fix: both blur passes are
// banded-matrix MFMAs (v_mfma_f32_16x16x32_f16, fp32 accum):
//   h-blur: D[r][c] = sum_k plane[r][chunk-8+k] * Wh[k][c],  Wh[k][c]=w[k-c-3]
//   v-blur: D[c][r] = sum_k ring[c][base+k]    * Wv[k][r],  Wv[k][r]=w[k-r]
// One MFMA covers the whole 11-tap window (K=32 >= 26 contributing rows).
// Data flow per 16-row step: async global_load_lds raw fp32 (dbuf, unchanged)
// -> elementwise (u=p^2+t^2, v=p*t, cvt fp16, mask edges) -> fp16 planes
// [4][16][88] -> h-blur MFMA -> fp16 ring, COLUMN-major [4][64 cols][56 slots]
// (D lane layout makes the transposed store natural: 2x ds_write_b32/qty)
// -> v-blur MFMA reads ds_read_b128 along the column -> fp32 mu/U/V -> SSIM.
// Ring stride 56 (not 48) => all wide LDS ops <=2-way bank aliased (free).
// Weight fragments built once in VGPRs; fp16 weight-sum drift corrected by
// compile-time cs = 1/s^2. Block 256 (4 waves x 16-col chunk), stripe 64x128.

#define WIDTH  512
#define HEIGHT 512
#define TW 64
#define SH 128
#define RING 48                  // logical ring rows (mod-48 arithmetic)
#define RST 56                   // physical slot stride (bank dispersion)
#define TILES_X 8
#define TILES_Y (HEIGHT / SH)    // 4
#define PLANES 48
#define NBLK (TILES_X * TILES_Y * PLANES)   // 1536
#define NPIXF 12582912.0f

typedef _Float16 half8_t __attribute__((ext_vector_type(8)));
typedef float f32x4_t __attribute__((ext_vector_type(4)));
typedef unsigned int u32x4_t __attribute__((ext_vector_type(4)));

// branchless-ish banded weight lookup (avoids runtime-indexed local array ->
// scratch); returns 0 outside [0,10]. Symmetric kernel.
__device__ __forceinline__ float wsel(int i) {
    unsigned a = (unsigned)i;
    float r = 0.f;
    if (a == 5u)              r = 0.26601168f;
    if (a == 4u || a == 6u)   r = 0.21300566f;
    if (a == 3u || a == 7u)   r = 0.10936069f;
    if (a == 2u || a == 8u)   r = 0.03600077f;
    if (a == 1u || a == 9u)   r = 0.00759881f;
    if (a == 0u || a == 10u)  r = 0.00102839f;
    return r;
}

__global__ __launch_bounds__(256)
void ssim_main(const float* __restrict__ pred,
               const float* __restrict__ tgt,
               float* __restrict__ partial) {
    __shared__ __align__(16) __half s_ring[4][TW][RST];   // 28672 B col-major
    __shared__ __align__(16) __half s_pl[4][16][88];      // 11264 B row-major
    __shared__ __align__(16) float  s_raw[2][2][16][80];  // 20480 B raw dbuf
    __shared__ float s_red[4];

    const int tid  = threadIdx.x;
    const int wv   = tid >> 6;          // wave id = 16-col chunk
    const int lane = tid & 63;
    const int r15  = lane & 15;
    const int g4   = lane >> 4;
    const int x0 = blockIdx.x * TW;
    const int y0 = blockIdx.y * SH;
    const size_t plane_off = (size_t)blockIdx.z * (WIDTH * HEIGHT);
    const float* P = pred + plane_off;
    const float* T = tgt + plane_off;
    const bool x_int = (x0 >= 8) && (x0 + TW + 8 <= WIDTH);

    // fp16 weight-sum correction (folds to a compile-time constant)
    const float s1 = 2.f * ((float)(_Float16)0.00102839f + (float)(_Float16)0.00759881f
                   + (float)(_Float16)0.03600077f + (float)(_Float16)0.10936069f
                   + (float)(_Float16)0.21300566f) + (float)(_Float16)0.26601168f;
    const float cs = 1.f / (s1 * s1);

    // Banded weight fragments (B operand: col = lane&15, k = (lane>>4)*8+j).
    half8_t Bh, Bv;
#pragma unroll
    for (int jj = 0; jj < 8; ++jj) {
        int k = g4 * 8 + jj;
        Bv[jj] = (_Float16)wsel(k - r15);        // Wv[k][r] = w[k-r]
        Bh[jj] = (_Float16)wsel(k - r15 - 3);    // Wh[k][c] = w[k-c-3]
    }

    // Async raw staging: 2 arrays x 16 rows x 80 cols fp32 = 10 x 1024 B
    // wave-wide transfers. LDS dest wave-uniform + lane*16 (HW rule).
    auto issue_async = [&](int buf, int gybase) {
#pragma unroll 1
        for (int l = wv; l < 10; l += 4) {
            int fi  = l * 256 + lane * 4;
            int arr = fi / 1280;                 // uniform per l
            int rem = fi - arr * 1280;
            int row = rem / 80;
            int col = rem - row * 80;
            int gy = gybase + row;
            if (gy < 0) gy = 0;
            if (gy > HEIGHT - 1) gy = HEIGHT - 1;
            int gx = x0 - 8 + col;
            if (gx < 0) gx = 0;
            if (gx > WIDTH - 4) gx = WIDTH - 4;
            const float* src = (arr == 0 ? P : T) + ((size_t)gy << 9) + gx;
            char* ldsbase = (char*)&s_raw[buf][0][0][0] + l * 1024;
            __builtin_amdgcn_global_load_lds(
                (const __attribute__((address_space(1))) unsigned int*)(const void*)src,
                (__attribute__((address_space(3))) unsigned int*)(void*)ldsbase,
                16, 0, 0);
        }
    };

    // elementwise: raw fp32 -> (p,t,u,v) fp16 planes, with edge masking.
    // Plane row r holds gy = gybase + r (rel row = gybase - (y0-5) + r).
    auto elementwise = [&](int buf, int gybase) {
        auto do_quad = [&](int row, int cq) {
            int gy = gybase + row;
            float4 pv = *(const float4*)&s_raw[buf][0][row][cq * 4];
            float4 tv = *(const float4*)&s_raw[buf][1][row][cq * 4];
            if ((unsigned)gy >= (unsigned)HEIGHT) {
                pv.x = pv.y = pv.z = pv.w = 0.f;
                tv.x = tv.y = tv.z = tv.w = 0.f;
            } else if (!x_int) {
                int gx0 = x0 - 8 + cq * 4;
                if ((unsigned)(gx0 + 0) >= (unsigned)WIDTH) { pv.x = 0.f; tv.x = 0.f; }
                if ((unsigned)(gx0 + 1) >= (unsigned)WIDTH) { pv.y = 0.f; tv.y = 0.f; }
                if ((unsigned)(gx0 + 2) >= (unsigned)WIDTH) { pv.z = 0.f; tv.z = 0.f; }
                if ((unsigned)(gx0 + 3) >= (unsigned)WIDTH) { pv.w = 0.f; tv.w = 0.f; }
            }
            float u0 = fmaf(pv.x, pv.x, tv.x * tv.x), v0 = pv.x * tv.x;
            float u1 = fmaf(pv.y, pv.y, tv.y * tv.y), v1 = pv.y * tv.y;
            float u2 = fmaf(pv.z, pv.z, tv.z * tv.z), v2 = pv.z * tv.z;
            float u3 = fmaf(pv.w, pv.w, tv.w * tv.w), v3 = pv.w * tv.w;
            uint2 wp, wt, wu, wvv;
            wp.x  = __builtin_bit_cast(unsigned, __floats2half2_rn(pv.x, pv.y));
            wp.y  = __builtin_bit_cast(unsigned, __floats2half2_rn(pv.z, pv.w));
            wt.x  = __builtin_bit_cast(unsigned, __floats2half2_rn(tv.x, tv.y));
            wt.y  = __builtin_bit_cast(unsigned, __floats2half2_rn(tv.z, tv.w));
            wu.x  = __builtin_bit_cast(unsigned, __floats2half2_rn(u0, u1));
            wu.y  = __builtin_bit_cast(unsigned, __floats2half2_rn(u2, u3));
            wvv.x = __builtin_bit_cast(unsigned, __floats2half2_rn(v0, v1));
            wvv.y = __builtin_bit_cast(unsigned, __floats2half2_rn(v2, v3));
            *(uint2*)&s_pl[0][row][cq * 4] = wp;
            *(uint2*)&s_pl[1][row][cq * 4] = wt;
            *(uint2*)&s_pl[2][row][cq * 4] = wu;
            *(uint2*)&s_pl[3][row][cq * 4] = wvv;
        };
        do_quad(tid >> 4, tid & 15);                 // cols 0..63
        if (tid < 64) do_quad(tid >> 2, 16 + (tid & 3));  // cols 64..79
    };

    // h-blur MFMA: planes -> ring (transposed store). Plane row r <-> rel row
    // relbase + r. D: lane holds rows 4*g4+reg, col = r15 (within chunk).
    auto hblur_store = [&](int relbase) {
        int s0 = relbase + 4 * g4;
        if (s0 >= 96) s0 -= 96;
        if (s0 >= 48) s0 -= 48;
        int s1b = s0 + 2; if (s1b >= 48) s1b -= 48;
        const int colA = (wv << 4) + r15;
        const int acol = (wv << 4) + g4 * 8;
#pragma unroll
        for (int q = 0; q < 4; ++q) {
            u32x4_t ra = *(const u32x4_t*)&s_pl[q][r15][acol];
            f32x4_t z = {0.f, 0.f, 0.f, 0.f};
            f32x4_t d = __builtin_amdgcn_mfma_f32_16x16x32_f16(
                __builtin_bit_cast(half8_t, ra), Bh, z, 0, 0, 0);
            unsigned p01 = __builtin_bit_cast(unsigned, __floats2half2_rn(d[0], d[1]));
            unsigned p23 = __builtin_bit_cast(unsigned, __floats2half2_rn(d[2], d[3]));
            *(unsigned*)&s_ring[q][colA][s0]  = p01;
            *(unsigned*)&s_ring[q][colA][s1b] = p23;
        }
    };

    float lsum = 0.f;

    // v-blur MFMA + SSIM. Reads rel rows 16j..16j+31 (k=26..31 zero-weight
    // pads; slots hold stale-but-finite prior-generation data). D: lane holds
    // out row = 16j + r15, cols = chunk + 4*g4 + reg.
    auto vblur_ssim = [&](int jstep) {
        int sg = 16 * jstep + 8 * g4;
        if (sg >= 96) sg -= 96;
        if (sg >= 48) sg -= 48;
        const int colA = (wv << 4) + r15;
        f32x4_t acc[4];
#pragma unroll
        for (int q = 0; q < 4; ++q) {
            u32x4_t ra = *(const u32x4_t*)&s_ring[q][colA][sg];
            f32x4_t z = {0.f, 0.f, 0.f, 0.f};
            acc[q] = __builtin_amdgcn_mfma_f32_16x16x32_f16(
                __builtin_bit_cast(half8_t, ra), Bv, z, 0, 0, 0);
        }
#pragma unroll
        for (int r = 0; r < 4; ++r) {
            float mp = acc[0][r] * cs, mt = acc[1][r] * cs;
            float U  = acc[2][r] * cs, V  = acc[3][r] * cs;
            float mpt = mp * mt;
            float B2  = fmaf(mp, mp, mt * mt);
            float spt  = V - mpt;
            float ssum = U - B2;
            float num = fmaf(2.f, mpt, 1e-4f) * fmaf(2.f, spt, 9e-4f);
            float den = (B2 + 1e-4f) * (ssum + 9e-4f);
            lsum += __fdividef(num, den);
        }
    };

    // ---- Prologue: fill ring rel rows 0..25, zero the pad slots ----
    issue_async(0, y0 - 5);                      // raw for rel 0..15
    {
        u32x4_t z4 = {0u, 0u, 0u, 0u};
#pragma unroll 1
        for (int i = tid; i < (int)(sizeof(s_ring) / 16); i += 256)
            ((u32x4_t*)s_ring)[i] = z4;          // finite pads (never NaN)
    }
    __syncthreads();                             // drains buf0 + zero done
    issue_async(1, y0 + 5);                      // raw for rel 10..25
    elementwise(0, y0 - 5);
    __syncthreads();                             // planes ready (drains buf1)
    hblur_store(0);                              // ring rel 0..15
    __syncthreads();
    issue_async(0, y0 + 21);                     // step-0 raw (rel 26..41)
    elementwise(1, y0 + 5);
    __syncthreads();
    hblur_store(10);                             // ring rel 10..25
    __syncthreads();                             // drains buf0

    // ---- Main loop: 8 steps of 16 output rows ----
#pragma unroll 1
    for (int j = 0; j < 8; ++j) {
        if (j < 6) issue_async((j + 1) & 1, y0 + 16 * (j + 1) + 21);
        if (j < 7) elementwise(j & 1, y0 + 16 * j + 21);
        vblur_ssim(j);
        __syncthreads();                         // planes -> h-blur handoff
        if (j < 7) hblur_store(16 * j + 26);
        __syncthreads();                         // ring handoff + async drain
    }

    // ---- Block reduction -> one partial per block ----
#pragma unroll
    for (int off = 32; off > 0; off >>= 1) lsum += __shfl_down(lsum, off);
    if ((tid & 63) == 0) s_red[tid >> 6] = lsum;
    __syncthreads();
    if (tid == 0) {
        partial[(blockIdx.z * TILES_Y + blockIdx.y) * TILES_X + blockIdx.x] =
            s_red[0] + s_red[1] + s_red[2] + s_red[3];
    }
}

__global__ __launch_bounds__(256)
void ssim_final(const float* __restrict__ partial, float* __restrict__ out) {
    __shared__ float s_red[4];
    float s = 0.f;
    for (int i = threadIdx.x; i < NBLK; i += 256) s += partial[i];
#pragma unroll
    for (int off = 32; off > 0; off >>= 1) s += __shfl_down(s, off);
    if ((threadIdx.x & 63) == 0) s_red[threadIdx.x >> 6] = s;
    __syncthreads();
    if (threadIdx.x == 0) {
        float total = s_red[0] + s_red[1] + s_red[2] + s_red[3];
        out[0] = 1.0f - total / NPIXF;
    }
}

extern "C" void kernel_launch(void* const* d_in, const int* in_sizes, int n_in,
                              void* d_out, int out_size, void* d_ws, size_t ws_size,
                              hipStream_t stream) {
    const float* pred = (const float*)d_in[0];
    const float* tgt  = (const float*)d_in[1];
    float* partial = (float*)d_ws;   // NBLK floats, fully rewritten each call

    dim3 grid(TILES_X, TILES_Y, PLANES);
    ssim_main<<<grid, dim3(256), 0, stream>>>(pred, tgt, partial);
    ssim_final<<<1, dim3(256), 0, stream>>>(partial, (float*)d_out);
}

// Round 2
// 130.601 us; speedup vs baseline: 1.2501x; 1.1727x over previous
//
#include <hip/hip_runtime.h>
#include <hip/hip_fp16.h>

// SSIM loss, fused, MFMA-blur v2. fp32 in [16,3,512,512], fp32 scalar out.
// Round-1 postmortem: VALU 40%, MFMA 4%, HBM 19%, occupancy 19% (2 blk/CU,
// 60.9KB LDS) -> latency/barrier-bound; ring writes bank-conflicted (even
// banks only). Fixes:
//  (a) raw staging moved LDS -> registers (plain float4 loads issued one
//      barrier-region ahead, T14 split). LDS = ring 28.7K + planes 10.2K
//      = 38.9KB -> 4 blocks/CU (16 waves), VGPR capped 128 via
//      __launch_bounds__(256,4).
//  (b) generation bases all multiples of 4 (rel 0, 12, 16j+28) -> each
//      lane's 4 h-blur output rows = ONE aligned ds_write_b64; bank map
//      28*r15 + 2*g4 + {0,1} is balanced (4/bank = min). vblur b128 reads
//      stay balanced-8.
//  (c) step = {E(j)} bar {issue loads(j+1), H(j), V(j)} bar : H(j) writes
//      rel 16j+28..43 which V(j) only reads with zero-weight taps (k>=26),
//      so they share a region; planes single-buffered.
//  (d) fp16 weight-sum drift folded into scaled C1/C2 (a = s1^2):
//      num/den invariant under acc scaling.
// MFMA blurs (v_mfma_f32_16x16x32_f16, fp32 accum):
//   h: D[r][c] = sum_k plane[r][wv*16+k] * w[k-c-3]
//   v: D[c][r] = sum_k ring[c][16j+k]    * w[k-r]

#define WIDTH  512
#define HEIGHT 512
#define TW 64
#define SH 128
#define RING 48                  // logical ring rows (mod-48)
#define RST 56                   // physical slot stride (bank dispersion)
#define TILES_X 8
#define TILES_Y (HEIGHT / SH)    // 4
#define PLANES 48
#define NBLK (TILES_X * TILES_Y * PLANES)   // 1536
#define NPIXF 12582912.0f

typedef _Float16 half8_t __attribute__((ext_vector_type(8)));
typedef float f32x4_t __attribute__((ext_vector_type(4)));
typedef unsigned int u32x4_t __attribute__((ext_vector_type(4)));

// banded weight lookup; 0 outside [0,10]. Symmetric kernel.
__device__ __forceinline__ float wsel(int i) {
    unsigned a = (unsigned)i;
    float r = 0.f;
    if (a == 5u)              r = 0.26601168f;
    if (a == 4u || a == 6u)   r = 0.21300566f;
    if (a == 3u || a == 7u)   r = 0.10936069f;
    if (a == 2u || a == 8u)   r = 0.03600077f;
    if (a == 1u || a == 9u)   r = 0.00759881f;
    if (a == 0u || a == 10u)  r = 0.00102839f;
    return r;
}

__global__ __launch_bounds__(256, 4)
void ssim_main(const float* __restrict__ pred,
               const float* __restrict__ tgt,
               float* __restrict__ partial) {
    __shared__ __align__(16) __half s_ring[4][TW][RST];   // 28672 B col-major
    __shared__ __align__(16) __half s_pl[4][16][80];      // 10240 B row-major
    __shared__ float s_red[4];

    const int tid  = threadIdx.x;
    const int wv   = tid >> 6;          // wave id = 16-col chunk
    const int lane = tid & 63;
    const int r15  = lane & 15;
    const int g4   = lane >> 4;
    const int x0 = blockIdx.x * TW;
    const int y0 = blockIdx.y * SH;
    const size_t plane_off = (size_t)blockIdx.z * (WIDTH * HEIGHT);
    const float* P = pred + plane_off;
    const float* T = tgt + plane_off;
    const bool x_int = (x0 >= 8) && (x0 + TW + 8 <= WIDTH);

    // fp16 weight-sum per pass (compile-time): acc scale a = s1^2.
    const float s1 = 2.f * ((float)(_Float16)0.00102839f + (float)(_Float16)0.00759881f
                   + (float)(_Float16)0.03600077f + (float)(_Float16)0.10936069f
                   + (float)(_Float16)0.21300566f) + (float)(_Float16)0.26601168f;
    const float a   = s1 * s1;
    const float C1A = a * a * 1e-4f;
    const float C2A = a * a * 9e-4f;

    // Banded weight fragments (B operand: col = lane&15, k = (lane>>4)*8+j).
    half8_t Bh, Bv;
#pragma unroll
    for (int jj = 0; jj < 8; ++jj) {
        int k = g4 * 8 + jj;
        Bv[jj] = (_Float16)wsel(k - r15);        // Wv[k][r] = w[k-r]
        Bh[jj] = (_Float16)wsel(k - r15 - 3);    // Wh[k][c] = w[k-c-3]
    }

    // Per-thread raw quads: quad0 for all, quad1 for tid<64 (cols 64..79).
    const int  erow0 = tid >> 4, ecq0 = tid & 15;
    const bool e2    = tid < 64;
    const int  erow1 = tid >> 2, ecq1 = 16 + (tid & 3);

    auto ldquad = [&](int gybase, int row, int cq, float4& p, float4& t) {
        int gy = gybase + row;
        if (gy < 0) gy = 0;
        if (gy > HEIGHT - 1) gy = HEIGHT - 1;
        int gx = x0 - 8 + cq * 4;                // always mult of 4
        if (gx < 0) gx = 0;
        if (gx > WIDTH - 4) gx = WIDTH - 4;
        const size_t ro = (size_t)gy << 9;
        p = *(const float4*)(P + ro + gx);
        t = *(const float4*)(T + ro + gx);
    };
    auto load_gen = [&](int gybase, float4& p0, float4& t0,
                        float4& p1, float4& t1) {
        ldquad(gybase, erow0, ecq0, p0, t0);
        if (e2) ldquad(gybase, erow1, ecq1, p1, t1);
    };

    auto equad = [&](int gybase, int row, int cq, float4 pv, float4 tv) {
        int gy = gybase + row;
        if ((unsigned)gy >= (unsigned)HEIGHT) {
            pv.x = pv.y = pv.z = pv.w = 0.f;
            tv.x = tv.y = tv.z = tv.w = 0.f;
        } else if (!x_int) {
            int gx0 = x0 - 8 + cq * 4;
            if ((unsigned)(gx0 + 0) >= (unsigned)WIDTH) { pv.x = 0.f; tv.x = 0.f; }
            if ((unsigned)(gx0 + 1) >= (unsigned)WIDTH) { pv.y = 0.f; tv.y = 0.f; }
            if ((unsigned)(gx0 + 2) >= (unsigned)WIDTH) { pv.z = 0.f; tv.z = 0.f; }
            if ((unsigned)(gx0 + 3) >= (unsigned)WIDTH) { pv.w = 0.f; tv.w = 0.f; }
        }
        float u0 = fmaf(pv.x, pv.x, tv.x * tv.x), v0 = pv.x * tv.x;
        float u1 = fmaf(pv.y, pv.y, tv.y * tv.y), v1 = pv.y * tv.y;
        float u2 = fmaf(pv.z, pv.z, tv.z * tv.z), v2 = pv.z * tv.z;
        float u3 = fmaf(pv.w, pv.w, tv.w * tv.w), v3 = pv.w * tv.w;
        uint2 wp, wt, wu, wvv;
        wp.x  = __builtin_bit_cast(unsigned, __floats2half2_rn(pv.x, pv.y));
        wp.y  = __builtin_bit_cast(unsigned, __floats2half2_rn(pv.z, pv.w));
        wt.x  = __builtin_bit_cast(unsigned, __floats2half2_rn(tv.x, tv.y));
        wt.y  = __builtin_bit_cast(unsigned, __floats2half2_rn(tv.z, tv.w));
        wu.x  = __builtin_bit_cast(unsigned, __floats2half2_rn(u0, u1));
        wu.y  = __builtin_bit_cast(unsigned, __floats2half2_rn(u2, u3));
        wvv.x = __builtin_bit_cast(unsigned, __floats2half2_rn(v0, v1));
        wvv.y = __builtin_bit_cast(unsigned, __floats2half2_rn(v2, v3));
        *(uint2*)&s_pl[0][row][cq * 4] = wp;
        *(uint2*)&s_pl[1][row][cq * 4] = wt;
        *(uint2*)&s_pl[2][row][cq * 4] = wu;
        *(uint2*)&s_pl[3][row][cq * 4] = wvv;
    };
    auto ewise = [&](int gybase, float4 p0, float4 t0, float4 p1, float4 t1) {
        equad(gybase, erow0, ecq0, p0, t0);
        if (e2) equad(gybase, erow1, ecq1, p1, t1);
    };

    // h-blur: planes -> ring (transposed). relbase MUST be mult of 4:
    // lane writes its 4 output rows (slots s0..s0+3) as one 8B ds_write_b64.
    auto hblur = [&](int relbase) {
        int s0 = relbase + 4 * g4;
        if (s0 >= 96) s0 -= 96; else if (s0 >= 48) s0 -= 48;
        const int colA = (wv << 4) + r15;
        const int acol = (wv << 4) + (g4 << 3);
#pragma unroll
        for (int q = 0; q < 4; ++q) {
            u32x4_t ra = *(const u32x4_t*)&s_pl[q][r15][acol];
            f32x4_t z = {0.f, 0.f, 0.f, 0.f};
            f32x4_t d = __builtin_amdgcn_mfma_f32_16x16x32_f16(
                __builtin_bit_cast(half8_t, ra), Bh, z, 0, 0, 0);
            uint2 pk;
            pk.x = __builtin_bit_cast(unsigned, __floats2half2_rn(d[0], d[1]));
            pk.y = __builtin_bit_cast(unsigned, __floats2half2_rn(d[2], d[3]));
            *(uint2*)&s_ring[q][colA][s0] = pk;
        }
    };

    float lsum = 0.f;

    // v-blur + SSIM. Reads rel 16j..16j+31 (k>=26 zero-weight; slots finite).
    auto vblur = [&](int jstep) {
        int sg = 16 * jstep + (g4 << 3);
        if (sg >= 96) sg -= 96; else if (sg >= 48) sg -= 48;
        const int colA = (wv << 4) + r15;
        f32x4_t acc[4];
#pragma unroll
        for (int q = 0; q < 4; ++q) {
            u32x4_t ra = *(const u32x4_t*)&s_ring[q][colA][sg];
            f32x4_t z = {0.f, 0.f, 0.f, 0.f};
            acc[q] = __builtin_amdgcn_mfma_f32_16x16x32_f16(
                __builtin_bit_cast(half8_t, ra), Bv, z, 0, 0, 0);
        }
#pragma unroll
        for (int r = 0; r < 4; ++r) {
            float mp = acc[0][r], mt = acc[1][r];       // scaled by a
            float U  = acc[2][r], V  = acc[3][r];
            float mpt  = mp * mt;                        // a^2 * true
            float B2   = fmaf(mp, mp, mt * mt);          // a^2 * true
            float S    = fmaf(a, V, -mpt);               // a^2 * sigma_pt
            float Ssum = fmaf(a, U, -B2);                // a^2 * (sp+st)
            float num = fmaf(2.f, mpt, C1A) * fmaf(2.f, S, C2A);
            float den = (B2 + C1A) * (Ssum + C2A);
            lsum += __fdividef(num, den);
        }
    };

    // ---- Prologue ----
    float4 ap0, at0, ap1, at1;      // gen set A
    float4 bp0, bt0, bp1, bt1;      // gen set B (prologue only)
    load_gen(y0 - 5, ap0, at0, ap1, at1);   // gen -2: rel 0..15
    load_gen(y0 + 7, bp0, bt0, bp1, bt1);   // gen -1: rel 12..27
    {
        u32x4_t z4 = {0u, 0u, 0u, 0u};
#pragma unroll
        for (int i = 0; i < 7; ++i)
            ((u32x4_t*)s_ring)[tid + 256 * i] = z4;   // finite pads
    }
    ewise(y0 - 5, ap0, at0, ap1, at1);
    __syncthreads();
    hblur(0);                                // ring rel 0..15
    load_gen(y0 + 23, ap0, at0, ap1, at1);   // gen 0
    __syncthreads();
    ewise(y0 + 7, bp0, bt0, bp1, bt1);
    __syncthreads();
    hblur(12);                               // ring rel 12..27
    __syncthreads();

    // ---- Main loop: 8 steps of 16 output rows ----
#pragma unroll 1
    for (int j = 0; j < 8; ++j) {
        if (j < 7) ewise(y0 + 16 * j + 23, ap0, at0, ap1, at1);
        __syncthreads();
        if (j < 6) load_gen(y0 + 16 * (j + 1) + 23, ap0, at0, ap1, at1);
        if (j < 7) hblur(16 * j + 28);       // ring rel 16j+28..43
        vblur(j);                            // reads rel 16j..16j+25 (+pads)
        __syncthreads();
    }

    // ---- Block reduction -> one partial per block ----
#pragma unroll
    for (int off = 32; off > 0; off >>= 1) lsum += __shfl_down(lsum, off);
    if ((tid & 63) == 0) s_red[tid >> 6] = lsum;
    __syncthreads();
    if (tid == 0) {
        partial[(blockIdx.z * TILES_Y + blockIdx.y) * TILES_X + blockIdx.x] =
            s_red[0] + s_red[1] + s_red[2] + s_red[3];
    }
}

__global__ __launch_bounds__(256)
void ssim_final(const float* __restrict__ partial, float* __restrict__ out) {
    __shared__ float s_red[4];
    float s = 0.f;
    for (int i = threadIdx.x; i < NBLK; i += 256) s += partial[i];
#pragma unroll
    for (int off = 32; off > 0; off >>= 1) s += __shfl_down(s, off);
    if ((threadIdx.x & 63) == 0) s_red[threadIdx.x >> 6] = s;
    __syncthreads();
    if (threadIdx.x == 0) {
        float total = s_red[0] + s_red[1] + s_red[2] + s_red[3];
        out[0] = 1.0f - total / NPIXF;
    }
}

extern "C" void kernel_launch(void* const* d_in, const int* in_sizes, int n_in,
                              void* d_out, int out_size, void* d_ws, size_t ws_size,
                              hipStream_t stream) {
    const float* pred = (const float*)d_in[0];
    const float* tgt  = (const float*)d_in[1];
    float* partial = (float*)d_ws;   // NBLK floats, fully rewritten each call

    dim3 grid(TILES_X, TILES_Y, PLANES);
    ssim_main<<<grid, dim3(256), 0, stream>>>(pred, tgt, partial);
    ssim_final<<<1, dim3(256), 0, stream>>>(partial, (float*)d_out);
}